// Round 1
// baseline (3173.656 us; speedup 1.0000x reference)
//
#include <hip/hip_runtime.h>
#include <math.h>

// Problem constants (fixed by setup_inputs)
#define N_GRD 4
#define M_SAT 32
#define C_CH  32
#define HK    64
#define WK    64
#define HO    65
#define WO    65
#define SAMPLE_ELEMS (C_CH * HK * WK)   // 131072
#define CORR_ELEMS   (M_SAT * N_GRD * HO * WO)  // 540800

// ws layout in floats
#define WS_INV   0                       // 64 floats (36 used: 0..3 grd, 4..35 sat)
#define WS_SATS  64                      // 32 * 65*65 = 135200
#define WS_CORR  (64 + M_SAT * HO * WO)  // 135264; CORR_ELEMS floats

// ---------------------------------------------------------------------------
// K1: per-sample inverse L2 norms.  36 blocks: 0..3 grd, 4..35 sat.
// ---------------------------------------------------------------------------
__global__ __launch_bounds__(256) void norms_kernel(const float* __restrict__ grd,
                                                    const float* __restrict__ sat,
                                                    float* __restrict__ inv) {
    int b = blockIdx.x;
    const float* base = (b < N_GRD) ? (grd + (size_t)b * SAMPLE_ELEMS)
                                    : (sat + (size_t)(b - N_GRD) * SAMPLE_ELEMS);
    const float4* v = reinterpret_cast<const float4*>(base);
    float ss = 0.0f;
    for (int p = threadIdx.x; p < SAMPLE_ELEMS / 4; p += 256) {
        float4 q = v[p];
        ss += q.x * q.x + q.y * q.y + q.z * q.z + q.w * q.w;
    }
    for (int off = 32; off > 0; off >>= 1) ss += __shfl_down(ss, off);
    __shared__ float ls[4];
    int lane = threadIdx.x & 63, w = threadIdx.x >> 6;
    if (lane == 0) ls[w] = ss;
    __syncthreads();
    if (threadIdx.x == 0) {
        float t = ls[0] + ls[1] + ls[2] + ls[3];
        float n = fmaxf(sqrtf(t), 1e-12f);
        inv[b] = 1.0f / n;
    }
}

// ---------------------------------------------------------------------------
// K2: per-m summed-area table of s2 = sum_c sat^2.  S is 65x65 exclusive SAT.
// ---------------------------------------------------------------------------
__global__ __launch_bounds__(256) void sat_s2_kernel(const float* __restrict__ sat,
                                                     float* __restrict__ S) {
    int m = blockIdx.x;
    __shared__ float s2[64][65];  // +1 pad
    const float* base = sat + (size_t)m * SAMPLE_ELEMS;
    for (int p = threadIdx.x; p < HK * WK; p += 256) {
        float s = 0.0f;
        for (int c = 0; c < C_CH; ++c) {
            float v = base[c * (HK * WK) + p];
            s += v * v;
        }
        s2[p >> 6][p & 63] = s;
    }
    __syncthreads();
    if (threadIdx.x < 64) {  // row prefix
        int r = threadIdx.x;
        float run = 0.0f;
        for (int w = 0; w < 64; ++w) { run += s2[r][w]; s2[r][w] = run; }
    }
    __syncthreads();
    if (threadIdx.x < 64) {  // col prefix
        int c = threadIdx.x;
        float run = 0.0f;
        for (int h = 0; h < 64; ++h) { run += s2[h][c]; s2[h][c] = run; }
    }
    __syncthreads();
    float* Sm = S + (size_t)m * (HO * WO);
    for (int p = threadIdx.x; p < HO * WO; p += 256) {
        int r = p / 65, c = p - r * 65;
        Sm[p] = (r == 0 || c == 0) ? 0.0f : s2[r - 1][c - 1];
    }
}

// ---------------------------------------------------------------------------
// K3: main cross-correlation (raw, unnormalized).
// Grid: (m=32, ytile=5, cchunk=4).  Block 256 = 16tx x 16ty.
// Thread computes x = 5*tx..5*tx+4 (sliding window), y = 16*ytile+ty, all 4 n.
// satT holds the zero-padded sat channel window: row r -> orig row y0+r-32,
// col q -> orig col q-32.  gbuf[j][n] holds grd rows for current (c,i).
// ---------------------------------------------------------------------------
__global__ __launch_bounds__(256) void corr_kernel(const float* __restrict__ grd,
                                                   const float* __restrict__ sat,
                                                   float* __restrict__ corr) {
    __shared__ float satT[79 * 144];
    __shared__ float gbuf[64 * 4];

    const int m  = blockIdx.x;
    const int y0 = blockIdx.y * 16;
    const int c0 = blockIdx.z * 8;
    const int tid = threadIdx.x;
    const int tx = tid & 15, ty = tid >> 4;

    float acc0[5], acc1[5], acc2[5], acc3[5];
#pragma unroll
    for (int k = 0; k < 5; ++k) { acc0[k] = 0.f; acc1[k] = 0.f; acc2[k] = 0.f; acc3[k] = 0.f; }

    const float* satm = sat + (size_t)m * SAMPLE_ELEMS;
    const int gn = tid >> 6;        // n for grd staging
    const int gj = tid & 63;        // j for grd staging

    for (int cc = 0; cc < 8; ++cc) {
        const int c = c0 + cc;
        const float* satc = satm + c * (HK * WK);
        __syncthreads();  // previous-c readers of satT done
        for (int p = tid; p < 79 * 144; p += 256) {
            int r = p / 144;
            int col = p - r * 144;
            int orow = y0 + r - 32;
            int ocol = col - 32;
            float v = 0.0f;
            if (orow >= 0 && orow < HK && ocol >= 0 && ocol < WK)
                v = satc[orow * WK + ocol];
            satT[p] = v;
        }
        const float* gbase = grd + ((size_t)gn * C_CH + c) * (HK * WK) + gj;
        for (int i = 0; i < HK; ++i) {
            __syncthreads();  // satT staged (i==0) / previous gbuf readers done
            gbuf[gj * 4 + gn] = gbase[i * WK];
            __syncthreads();  // gbuf ready
            const float* srow = satT + (ty + i) * 144 + tx * 5;
            float s0 = srow[0], s1 = srow[1], s2 = srow[2], s3 = srow[3];
#pragma unroll 8
            for (int j = 0; j < WK; ++j) {
                float s4 = srow[4 + j];
                float4 g = *reinterpret_cast<const float4*>(gbuf + 4 * j);
                acc0[0] = fmaf(g.x, s0, acc0[0]);
                acc0[1] = fmaf(g.x, s1, acc0[1]);
                acc0[2] = fmaf(g.x, s2, acc0[2]);
                acc0[3] = fmaf(g.x, s3, acc0[3]);
                acc0[4] = fmaf(g.x, s4, acc0[4]);
                acc1[0] = fmaf(g.y, s0, acc1[0]);
                acc1[1] = fmaf(g.y, s1, acc1[1]);
                acc1[2] = fmaf(g.y, s2, acc1[2]);
                acc1[3] = fmaf(g.y, s3, acc1[3]);
                acc1[4] = fmaf(g.y, s4, acc1[4]);
                acc2[0] = fmaf(g.z, s0, acc2[0]);
                acc2[1] = fmaf(g.z, s1, acc2[1]);
                acc2[2] = fmaf(g.z, s2, acc2[2]);
                acc2[3] = fmaf(g.z, s3, acc2[3]);
                acc2[4] = fmaf(g.z, s4, acc2[4]);
                acc3[0] = fmaf(g.w, s0, acc3[0]);
                acc3[1] = fmaf(g.w, s1, acc3[1]);
                acc3[2] = fmaf(g.w, s2, acc3[2]);
                acc3[3] = fmaf(g.w, s3, acc3[3]);
                acc3[4] = fmaf(g.w, s4, acc3[4]);
                s0 = s1; s1 = s2; s2 = s3; s3 = s4;
            }
        }
    }

    const int y = y0 + ty;
    if (y < HO) {
#pragma unroll
        for (int n = 0; n < 4; ++n) {
            const float* a = (n == 0) ? acc0 : (n == 1) ? acc1 : (n == 2) ? acc2 : acc3;
            float* dst = corr + (((size_t)m * N_GRD + n) * HO + y) * WO;
#pragma unroll
            for (int k = 0; k < 5; ++k) {
                int x = tx * 5 + k;
                if (x < WO) atomicAdd(dst + x, a[k]);
            }
        }
    }
}

// ---------------------------------------------------------------------------
// K4: normalize, divide by denom, max+argmax per (m,n), write outputs.
// out[0..127] = similarity [M,N]; out[128..383] = shift_meters [M,N,2].
// ---------------------------------------------------------------------------
__global__ __launch_bounds__(256) void epilogue_kernel(const float* __restrict__ corr,
                                                       const float* __restrict__ S,
                                                       const float* __restrict__ inv,
                                                       const int* __restrict__ unc,
                                                       float* __restrict__ out) {
    const int m = blockIdx.x >> 2;
    const int n = blockIdx.x & 3;
    const int tid = threadIdx.x;
    const float u = (float)unc[0];
    const float ign = inv[n];
    const float isn = inv[N_GRD + m];
    const float* Sm = S + (size_t)m * (HO * WO);
    const float* cmn = corr + ((size_t)m * N_GRD + n) * (HO * WO);

    float best = -3.4e38f;
    int bidx = 0;
    for (int p = tid; p < HO * WO; p += 256) {
        int y = p / 65;
        int x = p - y * 65;
        float num = cmn[p] * ign * isn;
        int r0 = max(0, y - 32), r1 = min(64, y + 32);
        int q0 = max(0, x - 32), q1 = min(64, x + 32);
        float ps = Sm[r1 * 65 + q1] - Sm[r0 * 65 + q1] - Sm[r1 * 65 + q0] + Sm[r0 * 65 + q0];
        float denom = fmaxf(sqrtf(ps) * isn * u, 1e-12f);
        float val = num / denom;
        if (val > best) { best = val; bidx = p; }  // first occurrence kept
    }
    __shared__ float bv[256];
    __shared__ int   bi[256];
    bv[tid] = best; bi[tid] = bidx;
    __syncthreads();
    for (int s = 128; s > 0; s >>= 1) {
        if (tid < s) {
            float ov = bv[tid + s]; int oi = bi[tid + s];
            if (ov > bv[tid] || (ov == bv[tid] && oi < bi[tid])) { bv[tid] = ov; bi[tid] = oi; }
        }
        __syncthreads();
    }
    if (tid == 0) {
        out[m * N_GRD + n] = bv[0];
        int row = bi[0] / 65;
        int col = bi[0] - row * 65;
        float half = 32.5f;
        float pr = -((float)row - half);
        float pc = (float)col - half;
        // mirror ref arithmetic: (p * 0.2) * 512 / 128
        out[128 + (m * N_GRD + n) * 2 + 0] = ((pr * 0.2f) * 512.0f) * (1.0f / 128.0f);
        out[128 + (m * N_GRD + n) * 2 + 1] = ((pc * 0.2f) * 512.0f) * (1.0f / 128.0f);
    }
}

// ---------------------------------------------------------------------------
extern "C" void kernel_launch(void* const* d_in, const int* in_sizes, int n_in,
                              void* d_out, int out_size, void* d_ws, size_t ws_size,
                              hipStream_t stream) {
    const float* grd = (const float*)d_in[0];
    const float* sat = (const float*)d_in[1];
    const int*   unc = (const int*)d_in[2];
    float* out = (float*)d_out;
    float* ws  = (float*)d_ws;

    float* inv  = ws + WS_INV;
    float* S    = ws + WS_SATS;
    float* corr = ws + WS_CORR;   // total ws use: ~2.7 MB

    norms_kernel<<<M_SAT + N_GRD, 256, 0, stream>>>(grd, sat, inv);
    sat_s2_kernel<<<M_SAT, 256, 0, stream>>>(sat, S);
    hipMemsetAsync(corr, 0, (size_t)CORR_ELEMS * sizeof(float), stream);
    corr_kernel<<<dim3(M_SAT, 5, 4), 256, 0, stream>>>(grd, sat, corr);
    epilogue_kernel<<<M_SAT * N_GRD, 256, 0, stream>>>(corr, S, inv, unc, out);
}

// Round 2
// 641.482 us; speedup vs baseline: 4.9474x; 4.9474x over previous
//
#include <hip/hip_runtime.h>
#include <math.h>

#define N_GRD 4
#define M_SAT 32
#define C_CH  32
#define HK    64
#define WK    64
#define HO    65
#define WO    65
#define SAMPLE_ELEMS (C_CH * HK * WK)

typedef _Float16 h8 __attribute__((ext_vector_type(8)));
typedef float    f4 __attribute__((ext_vector_type(4)));
typedef unsigned int u32;

// ---- ws layout (float units) ----
#define OFF_INV   0
#define OFF_S     64
#define OFF_CANDV 135264              // 64 + 32*4225
#define OFF_CANDI 135776
#define OFF_PART  136288
#define PART_FLOATS 6553600           // 8 * 32 * 5 * 5 * 4 * 256
#define OFF_G2F   (OFF_PART + PART_FLOATS)
#define G2_HALFS  1736704             // 2cp * 8cq * 64i * 4n * 106js * 4c

// ---------------------------------------------------------------------------
// K0: per-sample inverse L2 norms.  36 blocks: 0..3 grd, 4..35 sat.
// ---------------------------------------------------------------------------
__global__ __launch_bounds__(256) void norms_kernel(const float* __restrict__ grd,
                                                    const float* __restrict__ sat,
                                                    float* __restrict__ inv) {
    int b = blockIdx.x;
    const float* base = (b < N_GRD) ? (grd + (size_t)b * SAMPLE_ELEMS)
                                    : (sat + (size_t)(b - N_GRD) * SAMPLE_ELEMS);
    const float4* v = reinterpret_cast<const float4*>(base);
    float ss = 0.0f;
    for (int p = threadIdx.x; p < SAMPLE_ELEMS / 4; p += 256) {
        float4 q = v[p];
        ss += q.x * q.x + q.y * q.y + q.z * q.z + q.w * q.w;
    }
    for (int off = 32; off > 0; off >>= 1) ss += __shfl_down(ss, off);
    __shared__ float ls[4];
    int lane = threadIdx.x & 63, w = threadIdx.x >> 6;
    if (lane == 0) ls[w] = ss;
    __syncthreads();
    if (threadIdx.x == 0) {
        float t = ls[0] + ls[1] + ls[2] + ls[3];
        inv[b] = 1.0f / fmaxf(sqrtf(t), 1e-12f);
    }
}

// ---------------------------------------------------------------------------
// K1: per-m summed-area table of s2 = sum_c sat^2.  S is 65x65 exclusive SAT.
// ---------------------------------------------------------------------------
__global__ __launch_bounds__(256) void sat_s2_kernel(const float* __restrict__ sat,
                                                     float* __restrict__ S) {
    int m = blockIdx.x;
    __shared__ float s2[64][65];
    const float* base = sat + (size_t)m * SAMPLE_ELEMS;
    for (int p = threadIdx.x; p < HK * WK; p += 256) {
        float s = 0.0f;
        for (int c = 0; c < C_CH; ++c) {
            float v = base[c * (HK * WK) + p];
            s += v * v;
        }
        s2[p >> 6][p & 63] = s;
    }
    __syncthreads();
    if (threadIdx.x < 64) {
        int r = threadIdx.x;
        float run = 0.0f;
        for (int w = 0; w < 64; ++w) { run += s2[r][w]; s2[r][w] = run; }
    }
    __syncthreads();
    if (threadIdx.x < 64) {
        int c = threadIdx.x;
        float run = 0.0f;
        for (int h = 0; h < 64; ++h) { run += s2[h][c]; s2[h][c] = run; }
    }
    __syncthreads();
    float* Sm = S + (size_t)m * (HO * WO);
    for (int p = threadIdx.x; p < HO * WO; p += 256) {
        int r = p / 65, c = p - r * 65;
        Sm[p] = (r == 0 || c == 0) ? 0.0f : s2[r - 1][c - 1];
    }
}

// ---------------------------------------------------------------------------
// K2: build g2 (fp16 Toeplitz source), layout [cp2][cq8][i64][n4][js106][c4].
// value at js = g[n][cq*4+c][i][j],  j = js - 16 - cp  (zeros outside [0,64)).
// Two parity copies (cp) keep every shifted 16B B-fragment read aligned.
// ---------------------------------------------------------------------------
__global__ __launch_bounds__(256) void g2_prep_kernel(const float* __restrict__ grd,
                                                      _Float16* __restrict__ g2) {
    int idx = blockIdx.x * 256 + threadIdx.x;
    if (idx >= G2_HALFS) return;
    int c = idx & 3; int t = idx >> 2;
    int js = t % 106; t /= 106;
    int n = t & 3; t >>= 2;
    int i = t & 63; t >>= 6;
    int cq = t & 7; int cp = t >> 3;
    int j = js - 16 - cp;
    float v = 0.0f;
    if (j >= 0 && j < 64)
        v = grd[(((size_t)n * 32 + (cq * 4 + c)) * 64 + i) * 64 + j];
    g2[idx] = (_Float16)v;
}

// ---------------------------------------------------------------------------
// K3: main MFMA correlation.  Grid (m=32, xs=5, z=8: h=z&1 qhalf, qt=z>>1 cquarter)
// Block 256 = 4 waves = i-quarters.  Per wave: 5 y-tiles x 4 n col-tiles,
// C rows = y, C cols = x-shift s, K = (c4, dq8).
// A LDS: [r128][q42pad][c4] fp16 (stride 42 kills 8-way bank conflicts).
// B LDS: [wi4][cp2][n4][js106][c4] fp16, staged via global_load_lds.
// Output: fp32 partials (no atomics) -> partial[hq][m][xs][t][n][s*16+row].
// ---------------------------------------------------------------------------
__global__ __launch_bounds__(256, 2) void corr_mfma_kernel(const float* __restrict__ sat,
                                                           const _Float16* __restrict__ g2,
                                                           float* __restrict__ partial) {
    __shared__ __align__(16) char lds[43008 + 28672];
    char* AB = lds;
    char* BB = lds + 43008;

    const int m  = blockIdx.x;
    const int xs = blockIdx.y;
    const int z  = blockIdx.z;
    const int h  = z & 1;
    const int qt = z >> 1;

    const int x00 = (xs < 4) ? 16 * xs : 49;
    const int qb  = (xs < 4) ? 16 * xs : 48;
    const int xoff = x00 - qb;
    const int qstage = qb + 40 * h;

    const int tid  = threadIdx.x;
    const int w    = tid >> 6;
    const int lane = tid & 63;
    const int s    = lane & 15;
    const int u    = lane >> 4;
    const int cp   = (s + xoff) & 1;

    f4 acc[5][4];
#pragma unroll
    for (int t = 0; t < 5; ++t)
#pragma unroll
        for (int n = 0; n < 4; ++n) { acc[t][n][0]=0.f; acc[t][n][1]=0.f; acc[t][n][2]=0.f; acc[t][n][3]=0.f; }

    // B lane base byte offset (excl n*848, qs*64):  js0 = 16+cp+40h+8qs+2u-s-xoff
    const int bbase = ((w * 2 + cp) * 4 * 106 + (16 + cp + 40 * h + 2 * u - s - xoff)) * 8;
    // A lane base (excl i*336, y0t*336, qs*64)
    const int abase0 = (lane & 15) * 336 + u * 16;

    for (int cqi = 0; cqi < 2; ++cqi) {
        const int cq = qt * 2 + cqi;
        __syncthreads();
        // ---- stage A: 128 rows x 21 granules (g==20 is stride pad -> zeros)
        for (int k = 0; k < 11; ++k) {
            int idx = k * 256 + tid;
            if (idx < 2688) {
                int r = idx / 21;
                int g = idx - r * 21;
                int q = qstage + 2 * g;
                h8 hv = {0, 0, 0, 0, 0, 0, 0, 0};
                if (g < 20 && r >= 32 && r < 96 && q >= 32 && q < 96) {
                    const float* sp = sat + (((size_t)(m * 32 + cq * 4)) * 64 + (r - 32)) * 64 + (q - 32);
                    float2 v0 = *(const float2*)(sp);
                    float2 v1 = *(const float2*)(sp + 4096);
                    float2 v2 = *(const float2*)(sp + 8192);
                    float2 v3 = *(const float2*)(sp + 12288);
                    hv[0] = (_Float16)v0.x; hv[1] = (_Float16)v1.x; hv[2] = (_Float16)v2.x; hv[3] = (_Float16)v3.x;
                    hv[4] = (_Float16)v0.y; hv[5] = (_Float16)v1.y; hv[6] = (_Float16)v2.y; hv[7] = (_Float16)v3.y;
                }
                *(h8*)(AB + idx * 16) = hv;
            }
        }
        for (int ii = 0; ii < 16; ++ii) {
            __syncthreads();  // A ready / prior B readers done
            // ---- stage B: 1696 granules via global_load_lds (16B)
            for (int k = 0; k < 7; ++k) {
                int idx = k * 256 + tid;
                if (idx < 1696) {
                    int wi = idx / 424;  int rm  = idx - wi * 424;
                    int cpp = rm / 212;  int rm2 = rm - cpp * 212;
                    int nn = rm2 / 53;   int jg  = rm2 - nn * 53;
                    int iw = wi * 16 + ii;
                    const _Float16* gsrc = g2 + (size_t)((((cpp * 8 + cq) * 64 + iw) * 4 + nn)) * 424 + jg * 8;
                    __builtin_amdgcn_global_load_lds(
                        (const __attribute__((address_space(1))) u32*)(const void*)gsrc,
                        (__attribute__((address_space(3))) u32*)(void*)(BB + k * 4096 + w * 1024),
                        16, 0, 0);
                }
            }
            __syncthreads();  // B ready (barrier drains vmcnt)
            const int i = w * 16 + ii;
            const char* Ab = AB + abase0 + i * 336;
            const char* Bb = BB + bbase;
#pragma unroll
            for (int qs = 0; qs < 5; ++qs) {
                h8 a0 = *(const h8*)(Ab + qs * 64);
                h8 a1 = *(const h8*)(Ab + qs * 64 + 5376);
                h8 a2 = *(const h8*)(Ab + qs * 64 + 10752);
                h8 a3 = *(const h8*)(Ab + qs * 64 + 16128);
                h8 a4 = *(const h8*)(Ab + qs * 64 + 16464);
                h8 b0 = *(const h8*)(Bb + qs * 64);
                h8 b1 = *(const h8*)(Bb + qs * 64 + 848);
                h8 b2 = *(const h8*)(Bb + qs * 64 + 1696);
                h8 b3 = *(const h8*)(Bb + qs * 64 + 2544);
                acc[0][0] = __builtin_amdgcn_mfma_f32_16x16x32_f16(a0, b0, acc[0][0], 0, 0, 0);
                acc[0][1] = __builtin_amdgcn_mfma_f32_16x16x32_f16(a0, b1, acc[0][1], 0, 0, 0);
                acc[0][2] = __builtin_amdgcn_mfma_f32_16x16x32_f16(a0, b2, acc[0][2], 0, 0, 0);
                acc[0][3] = __builtin_amdgcn_mfma_f32_16x16x32_f16(a0, b3, acc[0][3], 0, 0, 0);
                acc[1][0] = __builtin_amdgcn_mfma_f32_16x16x32_f16(a1, b0, acc[1][0], 0, 0, 0);
                acc[1][1] = __builtin_amdgcn_mfma_f32_16x16x32_f16(a1, b1, acc[1][1], 0, 0, 0);
                acc[1][2] = __builtin_amdgcn_mfma_f32_16x16x32_f16(a1, b2, acc[1][2], 0, 0, 0);
                acc[1][3] = __builtin_amdgcn_mfma_f32_16x16x32_f16(a1, b3, acc[1][3], 0, 0, 0);
                acc[2][0] = __builtin_amdgcn_mfma_f32_16x16x32_f16(a2, b0, acc[2][0], 0, 0, 0);
                acc[2][1] = __builtin_amdgcn_mfma_f32_16x16x32_f16(a2, b1, acc[2][1], 0, 0, 0);
                acc[2][2] = __builtin_amdgcn_mfma_f32_16x16x32_f16(a2, b2, acc[2][2], 0, 0, 0);
                acc[2][3] = __builtin_amdgcn_mfma_f32_16x16x32_f16(a2, b3, acc[2][3], 0, 0, 0);
                acc[3][0] = __builtin_amdgcn_mfma_f32_16x16x32_f16(a3, b0, acc[3][0], 0, 0, 0);
                acc[3][1] = __builtin_amdgcn_mfma_f32_16x16x32_f16(a3, b1, acc[3][1], 0, 0, 0);
                acc[3][2] = __builtin_amdgcn_mfma_f32_16x16x32_f16(a3, b2, acc[3][2], 0, 0, 0);
                acc[3][3] = __builtin_amdgcn_mfma_f32_16x16x32_f16(a3, b3, acc[3][3], 0, 0, 0);
                acc[4][0] = __builtin_amdgcn_mfma_f32_16x16x32_f16(a4, b0, acc[4][0], 0, 0, 0);
                acc[4][1] = __builtin_amdgcn_mfma_f32_16x16x32_f16(a4, b1, acc[4][1], 0, 0, 0);
                acc[4][2] = __builtin_amdgcn_mfma_f32_16x16x32_f16(a4, b2, acc[4][2], 0, 0, 0);
                acc[4][3] = __builtin_amdgcn_mfma_f32_16x16x32_f16(a4, b3, acc[4][3], 0, 0, 0);
            }
        }
    }

    // ---- store: cross-wave (i-quarter) reduce in LDS, then plain stores
    float* red = (float*)lds;
    const int pbase = (((h * 4 + qt) * 32 + m)) * 25600 + xs * 5120;
#pragma unroll
    for (int pass = 0; pass < 4; ++pass) {
        __syncthreads();
#pragma unroll
        for (int tp = 0; tp < 5; ++tp) {
            const int tn = pass * 5 + tp;
            *(f4*)(red + ((tp * 4 + w) * 64 + lane) * 4) = acc[tn >> 2][tn & 3];
        }
        __syncthreads();
        for (int slot = tid; slot < 320; slot += 256) {
            int tp = slot >> 6, ln = slot & 63;
            f4 sum = *(f4*)(red + ((tp * 4 + 0) * 64 + ln) * 4);
            sum = sum + *(f4*)(red + ((tp * 4 + 1) * 64 + ln) * 4);
            sum = sum + *(f4*)(red + ((tp * 4 + 2) * 64 + ln) * 4);
            sum = sum + *(f4*)(red + ((tp * 4 + 3) * 64 + ln) * 4);
            int tn = pass * 5 + tp;
            int ss = ln & 15, uu = ln >> 4;
            *(f4*)(partial + pbase + tn * 256 + ss * 16 + uu * 4) = sum;
        }
    }
}

// ---------------------------------------------------------------------------
// K4: reduce partials + normalize + top-4 candidates per (m,n).
// ---------------------------------------------------------------------------
__global__ __launch_bounds__(256) void epilogue_kernel(const float* __restrict__ partial,
                                                       const float* __restrict__ S,
                                                       const float* __restrict__ inv,
                                                       const int* __restrict__ unc,
                                                       float* __restrict__ candv,
                                                       int* __restrict__ candi) {
    const int b = blockIdx.x;
    const int m = b >> 2, n = b & 3;
    const int tid = threadIdx.x;
    const float uu = (float)unc[0];
    const float sc = inv[n] * inv[N_GRD + m];
    const float isn = inv[N_GRD + m];
    const float* Sm = S + (size_t)m * 4225;
    const float* pb = partial + m * 25600;

    float best = -3.4e38f;
    int bidx = 0;
    for (int p = tid; p < 4225; p += 256) {
        int y = p / 65, x = p - y * 65;
        int t = (y == 64) ? 4 : (y >> 4);
        int row = (y == 64) ? 15 : (y & 15);
        int xs2 = (x == 64) ? 4 : (x >> 4);
        int ss = (x == 64) ? 15 : (x & 15);
        int so = xs2 * 5120 + (t * 4 + n) * 256 + ss * 16 + row;
        float sum = 0.0f;
#pragma unroll
        for (int hq = 0; hq < 8; ++hq) sum += pb[hq * 819200 + so];
        float num = sum * sc;
        int r0 = max(0, y - 32), r1 = min(64, y + 32);
        int q0 = max(0, x - 32), q1 = min(64, x + 32);
        float ps = Sm[r1 * 65 + q1] - Sm[r0 * 65 + q1] - Sm[r1 * 65 + q0] + Sm[r0 * 65 + q0];
        float denom = fmaxf(sqrtf(ps) * isn * uu, 1e-12f);
        float v = num / denom;
        if (v > best) { best = v; bidx = p; }
    }
    __shared__ float bv[256]; __shared__ int bi[256];
    __shared__ float cv[256]; __shared__ int ci[256];
    __shared__ int winner;
    bv[tid] = best; bi[tid] = bidx;
    __syncthreads();
    for (int round = 0; round < 4; ++round) {
        cv[tid] = bv[tid]; ci[tid] = bi[tid];
        __syncthreads();
        for (int st = 128; st > 0; st >>= 1) {
            if (tid < st) {
                float ov = cv[tid + st]; int oi = ci[tid + st];
                if (ov > cv[tid] || (ov == cv[tid] && oi < ci[tid])) { cv[tid] = ov; ci[tid] = oi; }
            }
            __syncthreads();
        }
        if (tid == 0) { candv[b * 4 + round] = cv[0]; candi[b * 4 + round] = ci[0]; winner = ci[0]; }
        __syncthreads();
        if (bi[tid] == winner) bv[tid] = -3.4e38f;
        __syncthreads();
    }
}

// ---------------------------------------------------------------------------
// K5: exact fp32 refinement of candidates (top-1 always; others if within
// margin), then final outputs.  Margin 0.02|v0|+1e-4 is >>100x the fp16 noise.
// ---------------------------------------------------------------------------
__global__ __launch_bounds__(256) void refine_kernel(const float* __restrict__ grd,
                                                     const float* __restrict__ sat,
                                                     const float* __restrict__ S,
                                                     const float* __restrict__ inv,
                                                     const int* __restrict__ unc,
                                                     const float* __restrict__ candv,
                                                     const int* __restrict__ candi,
                                                     float* __restrict__ out) {
    const int b = blockIdx.x;
    const int m = b >> 2, n = b & 3;
    const int tid = threadIdx.x;
    const float uu = (float)unc[0];
    const float sc = inv[n] * inv[N_GRD + m];
    const float isn = inv[N_GRD + m];
    const float* Sm = S + (size_t)m * 4225;

    float v0 = candv[b * 4];
    float thr = v0 - (0.02f * fabsf(v0) + 1e-4f);
    int K = 1;
    if (candv[b * 4 + 1] >= thr) { K = 2;
        if (candv[b * 4 + 2] >= thr) { K = 3;
            if (candv[b * 4 + 3] >= thr) K = 4; } }

    __shared__ float ls[4];
    float bestv = -3.4e38f; int bestp = 0;
    for (int k = 0; k < K; ++k) {
        int p = candi[b * 4 + k];
        int y = p / 65, x = p - y * 65;
        float a = 0.0f;
        for (int t = 0; t < 8; ++t) {
            int cc = t * 256 + tid;
            int c = cc >> 6, i = cc & 63;
            int row = y + i - 32;
            if (row >= 0 && row < 64) {
                int jlo = max(0, 32 - x), jhi = min(64, 96 - x);
                const float* sp = sat + (((size_t)m * 32 + c) * 64 + row) * 64 + (x + jlo - 32);
                const float* gp = grd + (((size_t)n * 32 + c) * 64 + i) * 64 + jlo;
                for (int j = 0; j < jhi - jlo; ++j) a += sp[j] * gp[j];
            }
        }
        for (int off = 32; off > 0; off >>= 1) a += __shfl_down(a, off);
        if ((tid & 63) == 0) ls[tid >> 6] = a;
        __syncthreads();
        if (tid == 0) {
            float dot = ls[0] + ls[1] + ls[2] + ls[3];
            float num = dot * sc;
            int r0 = max(0, y - 32), r1 = min(64, y + 32);
            int q0 = max(0, x - 32), q1 = min(64, x + 32);
            float ps = Sm[r1 * 65 + q1] - Sm[r0 * 65 + q1] - Sm[r1 * 65 + q0] + Sm[r0 * 65 + q0];
            float denom = fmaxf(sqrtf(ps) * isn * uu, 1e-12f);
            float v = num / denom;
            if (v > bestv || (v == bestv && p < bestp)) { bestv = v; bestp = p; }
        }
        __syncthreads();
    }
    if (tid == 0) {
        out[m * N_GRD + n] = bestv;
        int row = bestp / 65, col = bestp - row * 65;
        float pr = -((float)row - 32.5f);
        float pc = (float)col - 32.5f;
        out[128 + (m * N_GRD + n) * 2 + 0] = ((pr * 0.2f) * 512.0f) * (1.0f / 128.0f);
        out[128 + (m * N_GRD + n) * 2 + 1] = ((pc * 0.2f) * 512.0f) * (1.0f / 128.0f);
    }
}

// ---------------------------------------------------------------------------
extern "C" void kernel_launch(void* const* d_in, const int* in_sizes, int n_in,
                              void* d_out, int out_size, void* d_ws, size_t ws_size,
                              hipStream_t stream) {
    const float* grd = (const float*)d_in[0];
    const float* sat = (const float*)d_in[1];
    const int*   unc = (const int*)d_in[2];
    float* out = (float*)d_out;
    float* ws  = (float*)d_ws;

    float* inv     = ws + OFF_INV;
    float* S       = ws + OFF_S;
    float* candv   = ws + OFF_CANDV;
    int*   candi   = (int*)(ws + OFF_CANDI);
    float* partial = ws + OFF_PART;
    _Float16* g2   = (_Float16*)(ws + OFF_G2F);   // ~30.2 MB total ws use

    norms_kernel<<<M_SAT + N_GRD, 256, 0, stream>>>(grd, sat, inv);
    sat_s2_kernel<<<M_SAT, 256, 0, stream>>>(sat, S);
    g2_prep_kernel<<<(G2_HALFS + 255) / 256, 256, 0, stream>>>(grd, g2);
    corr_mfma_kernel<<<dim3(M_SAT, 5, 8), 256, 0, stream>>>(sat, g2, partial);
    epilogue_kernel<<<M_SAT * N_GRD, 256, 0, stream>>>(partial, S, inv, unc, candv, candi);
    refine_kernel<<<M_SAT * N_GRD, 256, 0, stream>>>(grd, sat, S, inv, unc, candv, candi, out);
}

// Round 3
// 500.121 us; speedup vs baseline: 6.3458x; 1.2827x over previous
//
#include <hip/hip_runtime.h>
#include <math.h>

#define N_GRD 4
#define M_SAT 32
#define C_CH  32
#define HK    64
#define WK    64
#define HO    65
#define WO    65
#define SAMPLE_ELEMS (C_CH * HK * WK)

typedef _Float16 h8 __attribute__((ext_vector_type(8)));
typedef float    f4 __attribute__((ext_vector_type(4)));
typedef unsigned int u32;

// ---- ws layout (float units) ----
#define OFF_INV   0
#define OFF_S     64
#define OFF_CANDV 135264              // 64 + 32*4225
#define OFF_CANDI 135776
#define OFF_DOTS  136288              // 128*4 exact dots
#define OFF_PART  136800
#define PART_FLOATS 6553600           // 8 * 32 * 5 * 5 * 4 * 256
#define OFF_G2F   (OFF_PART + PART_FLOATS)
#define G2_HALFS  1736704             // 2cp * 8cq * 64i * 4n * 106js * 4c

// ---------------------------------------------------------------------------
// K0: per-sample inverse L2 norms.  36 blocks: 0..3 grd, 4..35 sat.
// ---------------------------------------------------------------------------
__global__ __launch_bounds__(256) void norms_kernel(const float* __restrict__ grd,
                                                    const float* __restrict__ sat,
                                                    float* __restrict__ inv) {
    int b = blockIdx.x;
    const float* base = (b < N_GRD) ? (grd + (size_t)b * SAMPLE_ELEMS)
                                    : (sat + (size_t)(b - N_GRD) * SAMPLE_ELEMS);
    const float4* v = reinterpret_cast<const float4*>(base);
    float ss = 0.0f;
    for (int p = threadIdx.x; p < SAMPLE_ELEMS / 4; p += 256) {
        float4 q = v[p];
        ss += q.x * q.x + q.y * q.y + q.z * q.z + q.w * q.w;
    }
    for (int off = 32; off > 0; off >>= 1) ss += __shfl_down(ss, off);
    __shared__ float ls[4];
    int lane = threadIdx.x & 63, w = threadIdx.x >> 6;
    if (lane == 0) ls[w] = ss;
    __syncthreads();
    if (threadIdx.x == 0) {
        float t = ls[0] + ls[1] + ls[2] + ls[3];
        inv[b] = 1.0f / fmaxf(sqrtf(t), 1e-12f);
    }
}

// ---------------------------------------------------------------------------
// K1: per-m summed-area table of s2 = sum_c sat^2.  S is 65x65 exclusive SAT.
// ---------------------------------------------------------------------------
__global__ __launch_bounds__(256) void sat_s2_kernel(const float* __restrict__ sat,
                                                     float* __restrict__ S) {
    int m = blockIdx.x;
    __shared__ float s2[64][65];
    const float* base = sat + (size_t)m * SAMPLE_ELEMS;
    for (int p = threadIdx.x; p < HK * WK; p += 256) {
        float s = 0.0f;
        for (int c = 0; c < C_CH; ++c) {
            float v = base[c * (HK * WK) + p];
            s += v * v;
        }
        s2[p >> 6][p & 63] = s;
    }
    __syncthreads();
    if (threadIdx.x < 64) {
        int r = threadIdx.x;
        float run = 0.0f;
        for (int w = 0; w < 64; ++w) { run += s2[r][w]; s2[r][w] = run; }
    }
    __syncthreads();
    if (threadIdx.x < 64) {
        int c = threadIdx.x;
        float run = 0.0f;
        for (int h = 0; h < 64; ++h) { run += s2[h][c]; s2[h][c] = run; }
    }
    __syncthreads();
    float* Sm = S + (size_t)m * (HO * WO);
    for (int p = threadIdx.x; p < HO * WO; p += 256) {
        int r = p / 65, c = p - r * 65;
        Sm[p] = (r == 0 || c == 0) ? 0.0f : s2[r - 1][c - 1];
    }
}

// ---------------------------------------------------------------------------
// K2: build g2 (fp16 Toeplitz source), layout [cp2][cq8][i64][n4][js106][c4].
// value at js = g[n][cq*4+c][i][j],  j = js - 16 - cp  (zeros outside [0,64)).
// ---------------------------------------------------------------------------
__global__ __launch_bounds__(256) void g2_prep_kernel(const float* __restrict__ grd,
                                                      _Float16* __restrict__ g2) {
    int idx = blockIdx.x * 256 + threadIdx.x;
    if (idx >= G2_HALFS) return;
    int c = idx & 3; int t = idx >> 2;
    int js = t % 106; t /= 106;
    int n = t & 3; t >>= 2;
    int i = t & 63; t >>= 6;
    int cq = t & 7; int cp = t >> 3;
    int j = js - 16 - cp;
    float v = 0.0f;
    if (j >= 0 && j < 64)
        v = grd[(((size_t)n * 32 + (cq * 4 + c)) * 64 + i) * 64 + j];
    g2[idx] = (_Float16)v;
}

// ---------------------------------------------------------------------------
// K3: main MFMA correlation (unchanged from R1).
// ---------------------------------------------------------------------------
__global__ __launch_bounds__(256, 2) void corr_mfma_kernel(const float* __restrict__ sat,
                                                           const _Float16* __restrict__ g2,
                                                           float* __restrict__ partial) {
    __shared__ __align__(16) char lds[43008 + 28672];
    char* AB = lds;
    char* BB = lds + 43008;

    const int m  = blockIdx.x;
    const int xs = blockIdx.y;
    const int z  = blockIdx.z;
    const int h  = z & 1;
    const int qt = z >> 1;

    const int x00 = (xs < 4) ? 16 * xs : 49;
    const int qb  = (xs < 4) ? 16 * xs : 48;
    const int xoff = x00 - qb;
    const int qstage = qb + 40 * h;

    const int tid  = threadIdx.x;
    const int w    = tid >> 6;
    const int lane = tid & 63;
    const int s    = lane & 15;
    const int u    = lane >> 4;
    const int cp   = (s + xoff) & 1;

    f4 acc[5][4];
#pragma unroll
    for (int t = 0; t < 5; ++t)
#pragma unroll
        for (int n = 0; n < 4; ++n) { acc[t][n][0]=0.f; acc[t][n][1]=0.f; acc[t][n][2]=0.f; acc[t][n][3]=0.f; }

    const int bbase = ((w * 2 + cp) * 4 * 106 + (16 + cp + 40 * h + 2 * u - s - xoff)) * 8;
    const int abase0 = (lane & 15) * 336 + u * 16;

    for (int cqi = 0; cqi < 2; ++cqi) {
        const int cq = qt * 2 + cqi;
        __syncthreads();
        for (int k = 0; k < 11; ++k) {
            int idx = k * 256 + tid;
            if (idx < 2688) {
                int r = idx / 21;
                int g = idx - r * 21;
                int q = qstage + 2 * g;
                h8 hv = {0, 0, 0, 0, 0, 0, 0, 0};
                if (g < 20 && r >= 32 && r < 96 && q >= 32 && q < 96) {
                    const float* sp = sat + (((size_t)(m * 32 + cq * 4)) * 64 + (r - 32)) * 64 + (q - 32);
                    float2 v0 = *(const float2*)(sp);
                    float2 v1 = *(const float2*)(sp + 4096);
                    float2 v2 = *(const float2*)(sp + 8192);
                    float2 v3 = *(const float2*)(sp + 12288);
                    hv[0] = (_Float16)v0.x; hv[1] = (_Float16)v1.x; hv[2] = (_Float16)v2.x; hv[3] = (_Float16)v3.x;
                    hv[4] = (_Float16)v0.y; hv[5] = (_Float16)v1.y; hv[6] = (_Float16)v2.y; hv[7] = (_Float16)v3.y;
                }
                *(h8*)(AB + idx * 16) = hv;
            }
        }
        for (int ii = 0; ii < 16; ++ii) {
            __syncthreads();
            for (int k = 0; k < 7; ++k) {
                int idx = k * 256 + tid;
                if (idx < 1696) {
                    int wi = idx / 424;  int rm  = idx - wi * 424;
                    int cpp = rm / 212;  int rm2 = rm - cpp * 212;
                    int nn = rm2 / 53;   int jg  = rm2 - nn * 53;
                    int iw = wi * 16 + ii;
                    const _Float16* gsrc = g2 + (size_t)((((cpp * 8 + cq) * 64 + iw) * 4 + nn)) * 424 + jg * 8;
                    __builtin_amdgcn_global_load_lds(
                        (const __attribute__((address_space(1))) u32*)(const void*)gsrc,
                        (__attribute__((address_space(3))) u32*)(void*)(BB + k * 4096 + w * 1024),
                        16, 0, 0);
                }
            }
            __syncthreads();
            const int i = w * 16 + ii;
            const char* Ab = AB + abase0 + i * 336;
            const char* Bb = BB + bbase;
#pragma unroll
            for (int qs = 0; qs < 5; ++qs) {
                h8 a0 = *(const h8*)(Ab + qs * 64);
                h8 a1 = *(const h8*)(Ab + qs * 64 + 5376);
                h8 a2 = *(const h8*)(Ab + qs * 64 + 10752);
                h8 a3 = *(const h8*)(Ab + qs * 64 + 16128);
                h8 a4 = *(const h8*)(Ab + qs * 64 + 16464);
                h8 b0 = *(const h8*)(Bb + qs * 64);
                h8 b1 = *(const h8*)(Bb + qs * 64 + 848);
                h8 b2 = *(const h8*)(Bb + qs * 64 + 1696);
                h8 b3 = *(const h8*)(Bb + qs * 64 + 2544);
                acc[0][0] = __builtin_amdgcn_mfma_f32_16x16x32_f16(a0, b0, acc[0][0], 0, 0, 0);
                acc[0][1] = __builtin_amdgcn_mfma_f32_16x16x32_f16(a0, b1, acc[0][1], 0, 0, 0);
                acc[0][2] = __builtin_amdgcn_mfma_f32_16x16x32_f16(a0, b2, acc[0][2], 0, 0, 0);
                acc[0][3] = __builtin_amdgcn_mfma_f32_16x16x32_f16(a0, b3, acc[0][3], 0, 0, 0);
                acc[1][0] = __builtin_amdgcn_mfma_f32_16x16x32_f16(a1, b0, acc[1][0], 0, 0, 0);
                acc[1][1] = __builtin_amdgcn_mfma_f32_16x16x32_f16(a1, b1, acc[1][1], 0, 0, 0);
                acc[1][2] = __builtin_amdgcn_mfma_f32_16x16x32_f16(a1, b2, acc[1][2], 0, 0, 0);
                acc[1][3] = __builtin_amdgcn_mfma_f32_16x16x32_f16(a1, b3, acc[1][3], 0, 0, 0);
                acc[2][0] = __builtin_amdgcn_mfma_f32_16x16x32_f16(a2, b0, acc[2][0], 0, 0, 0);
                acc[2][1] = __builtin_amdgcn_mfma_f32_16x16x32_f16(a2, b1, acc[2][1], 0, 0, 0);
                acc[2][2] = __builtin_amdgcn_mfma_f32_16x16x32_f16(a2, b2, acc[2][2], 0, 0, 0);
                acc[2][3] = __builtin_amdgcn_mfma_f32_16x16x32_f16(a2, b3, acc[2][3], 0, 0, 0);
                acc[3][0] = __builtin_amdgcn_mfma_f32_16x16x32_f16(a3, b0, acc[3][0], 0, 0, 0);
                acc[3][1] = __builtin_amdgcn_mfma_f32_16x16x32_f16(a3, b1, acc[3][1], 0, 0, 0);
                acc[3][2] = __builtin_amdgcn_mfma_f32_16x16x32_f16(a3, b2, acc[3][2], 0, 0, 0);
                acc[3][3] = __builtin_amdgcn_mfma_f32_16x16x32_f16(a3, b3, acc[3][3], 0, 0, 0);
                acc[4][0] = __builtin_amdgcn_mfma_f32_16x16x32_f16(a4, b0, acc[4][0], 0, 0, 0);
                acc[4][1] = __builtin_amdgcn_mfma_f32_16x16x32_f16(a4, b1, acc[4][1], 0, 0, 0);
                acc[4][2] = __builtin_amdgcn_mfma_f32_16x16x32_f16(a4, b2, acc[4][2], 0, 0, 0);
                acc[4][3] = __builtin_amdgcn_mfma_f32_16x16x32_f16(a4, b3, acc[4][3], 0, 0, 0);
            }
        }
    }

    float* red = (float*)lds;
    const int pbase = (((h * 4 + qt) * 32 + m)) * 25600 + xs * 5120;
#pragma unroll
    for (int pass = 0; pass < 4; ++pass) {
        __syncthreads();
#pragma unroll
        for (int tp = 0; tp < 5; ++tp) {
            const int tn = pass * 5 + tp;
            *(f4*)(red + ((tp * 4 + w) * 64 + lane) * 4) = acc[tn >> 2][tn & 3];
        }
        __syncthreads();
        for (int slot = tid; slot < 320; slot += 256) {
            int tp = slot >> 6, ln = slot & 63;
            f4 sum = *(f4*)(red + ((tp * 4 + 0) * 64 + ln) * 4);
            sum = sum + *(f4*)(red + ((tp * 4 + 1) * 64 + ln) * 4);
            sum = sum + *(f4*)(red + ((tp * 4 + 2) * 64 + ln) * 4);
            sum = sum + *(f4*)(red + ((tp * 4 + 3) * 64 + ln) * 4);
            int tn = pass * 5 + tp;
            int ss = ln & 15, uu = ln >> 4;
            *(f4*)(partial + pbase + tn * 256 + ss * 16 + uu * 4) = sum;
        }
    }
}

// ---------------------------------------------------------------------------
// K4: reduce partials + normalize + top-4 candidates per (m,n).
// ---------------------------------------------------------------------------
__global__ __launch_bounds__(256) void epilogue_kernel(const float* __restrict__ partial,
                                                       const float* __restrict__ S,
                                                       const float* __restrict__ inv,
                                                       const int* __restrict__ unc,
                                                       float* __restrict__ candv,
                                                       int* __restrict__ candi) {
    const int b = blockIdx.x;
    const int m = b >> 2, n = b & 3;
    const int tid = threadIdx.x;
    const float uu = (float)unc[0];
    const float sc = inv[n] * inv[N_GRD + m];
    const float isn = inv[N_GRD + m];
    const float* Sm = S + (size_t)m * 4225;
    const float* pb = partial + m * 25600;

    float best = -3.4e38f;
    int bidx = 0;
    for (int p = tid; p < 4225; p += 256) {
        int y = p / 65, x = p - y * 65;
        int t = (y == 64) ? 4 : (y >> 4);
        int row = (y == 64) ? 15 : (y & 15);
        int xs2 = (x == 64) ? 4 : (x >> 4);
        int ss = (x == 64) ? 15 : (x & 15);
        int so = xs2 * 5120 + (t * 4 + n) * 256 + ss * 16 + row;
        float sum = 0.0f;
#pragma unroll
        for (int hq = 0; hq < 8; ++hq) sum += pb[hq * 819200 + so];
        float num = sum * sc;
        int r0 = max(0, y - 32), r1 = min(64, y + 32);
        int q0 = max(0, x - 32), q1 = min(64, x + 32);
        float ps = Sm[r1 * 65 + q1] - Sm[r0 * 65 + q1] - Sm[r1 * 65 + q0] + Sm[r0 * 65 + q0];
        float denom = fmaxf(sqrtf(ps) * isn * uu, 1e-12f);
        float v = num / denom;
        if (v > best) { best = v; bidx = p; }
    }
    __shared__ float bv[256]; __shared__ int bi[256];
    __shared__ float cv[256]; __shared__ int ci[256];
    __shared__ int winner;
    bv[tid] = best; bi[tid] = bidx;
    __syncthreads();
    for (int round = 0; round < 4; ++round) {
        cv[tid] = bv[tid]; ci[tid] = bi[tid];
        __syncthreads();
        for (int st = 128; st > 0; st >>= 1) {
            if (tid < st) {
                float ov = cv[tid + st]; int oi = ci[tid + st];
                if (ov > cv[tid] || (ov == cv[tid] && oi < ci[tid])) { cv[tid] = ov; ci[tid] = oi; }
            }
            __syncthreads();
        }
        if (tid == 0) { candv[b * 4 + round] = cv[0]; candi[b * 4 + round] = ci[0]; winner = ci[0]; }
        __syncthreads();
        if (bi[tid] == winner) bv[tid] = -3.4e38f;
        __syncthreads();
    }
}

// ---------------------------------------------------------------------------
// K5a: exact fp32 dot for candidate slot (b,k), parallel + coalesced.
// Early-exits slots outside the fp16-noise margin (data-dependent but
// identical on every replay since inputs are restored).
// ---------------------------------------------------------------------------
__global__ __launch_bounds__(256) void refine_dot_kernel(const float* __restrict__ grd,
                                                         const float* __restrict__ sat,
                                                         const float* __restrict__ candv,
                                                         const int* __restrict__ candi,
                                                         float* __restrict__ dots) {
    const int b = blockIdx.x;
    const int k = blockIdx.y;
    const int m = b >> 2, n = b & 3;
    float v0 = candv[b * 4];
    float thr = v0 - (0.02f * fabsf(v0) + 1e-4f);
    if (k > 0 && candv[b * 4 + k] < thr) {
        if (threadIdx.x == 0) dots[b * 4 + k] = 0.0f;
        return;
    }
    int p = candi[b * 4 + k];
    int y = p / 65, x = p - y * 65;
    const int tid = threadIdx.x, lane = tid & 63, w = tid >> 6;
    int xj = x + lane - 32;                 // sat column this lane covers
    bool jv = (xj >= 0 && xj < 64);
    const float* sbase = sat + (size_t)m * SAMPLE_ELEMS + xj;
    const float* gbase = grd + (size_t)n * SAMPLE_ELEMS + lane;
    float acc = 0.0f;
    for (int pair = w; pair < 2048; pair += 4) {   // (c,i) pairs, 512 per wave
        int c = pair >> 6, i = pair & 63;
        int row = y + i - 32;
        if (jv && row >= 0 && row < 64) {
            float sv = sbase[(c * 64 + row) * 64];
            float gv = gbase[(c * 64 + i) * 64];
            acc = fmaf(sv, gv, acc);
        }
    }
    for (int off = 32; off > 0; off >>= 1) acc += __shfl_down(acc, off);
    __shared__ float ls[4];
    if (lane == 0) ls[w] = acc;
    __syncthreads();
    if (tid == 0) dots[b * 4 + k] = ls[0] + ls[1] + ls[2] + ls[3];
}

// ---------------------------------------------------------------------------
// K5b: pick best refined candidate per (m,n), write outputs.  1 block.
// ---------------------------------------------------------------------------
__global__ __launch_bounds__(128) void refine_pick_kernel(const float* __restrict__ S,
                                                          const float* __restrict__ inv,
                                                          const int* __restrict__ unc,
                                                          const float* __restrict__ candv,
                                                          const int* __restrict__ candi,
                                                          const float* __restrict__ dots,
                                                          float* __restrict__ out) {
    int b = threadIdx.x;
    if (b >= 128) return;
    const int m = b >> 2, n = b & 3;
    const float uu = (float)unc[0];
    const float sc = inv[n] * inv[N_GRD + m];
    const float isn = inv[N_GRD + m];
    const float* Sm = S + (size_t)m * 4225;
    float v0 = candv[b * 4];
    float thr = v0 - (0.02f * fabsf(v0) + 1e-4f);
    float bestv = -3.4e38f; int bestp = 0;
    for (int k = 0; k < 4; ++k) {
        if (k > 0 && candv[b * 4 + k] < thr) break;   // candv sorted desc
        int p = candi[b * 4 + k];
        int y = p / 65, x = p - y * 65;
        int r0 = max(0, y - 32), r1 = min(64, y + 32);
        int q0 = max(0, x - 32), q1 = min(64, x + 32);
        float ps = Sm[r1 * 65 + q1] - Sm[r0 * 65 + q1] - Sm[r1 * 65 + q0] + Sm[r0 * 65 + q0];
        float denom = fmaxf(sqrtf(ps) * isn * uu, 1e-12f);
        float v = dots[b * 4 + k] * sc / denom;
        if (v > bestv || (v == bestv && p < bestp)) { bestv = v; bestp = p; }
    }
    out[b] = bestv;
    int row = bestp / 65, col = bestp - row * 65;
    float pr = -((float)row - 32.5f);
    float pc = (float)col - 32.5f;
    out[128 + b * 2 + 0] = ((pr * 0.2f) * 512.0f) * (1.0f / 128.0f);
    out[128 + b * 2 + 1] = ((pc * 0.2f) * 512.0f) * (1.0f / 128.0f);
}

// ---------------------------------------------------------------------------
extern "C" void kernel_launch(void* const* d_in, const int* in_sizes, int n_in,
                              void* d_out, int out_size, void* d_ws, size_t ws_size,
                              hipStream_t stream) {
    const float* grd = (const float*)d_in[0];
    const float* sat = (const float*)d_in[1];
    const int*   unc = (const int*)d_in[2];
    float* out = (float*)d_out;
    float* ws  = (float*)d_ws;

    float* inv     = ws + OFF_INV;
    float* S       = ws + OFF_S;
    float* candv   = ws + OFF_CANDV;
    int*   candi   = (int*)(ws + OFF_CANDI);
    float* dots    = ws + OFF_DOTS;
    float* partial = ws + OFF_PART;
    _Float16* g2   = (_Float16*)(ws + OFF_G2F);   // ~30.2 MB total ws use

    norms_kernel<<<M_SAT + N_GRD, 256, 0, stream>>>(grd, sat, inv);
    sat_s2_kernel<<<M_SAT, 256, 0, stream>>>(sat, S);
    g2_prep_kernel<<<(G2_HALFS + 255) / 256, 256, 0, stream>>>(grd, g2);
    corr_mfma_kernel<<<dim3(M_SAT, 5, 8), 256, 0, stream>>>(sat, g2, partial);
    epilogue_kernel<<<M_SAT * N_GRD, 256, 0, stream>>>(partial, S, inv, unc, candv, candi);
    refine_dot_kernel<<<dim3(128, 4), 256, 0, stream>>>(grd, sat, candv, candi, dots);
    refine_pick_kernel<<<1, 128, 0, stream>>>(S, inv, unc, candv, candi, dots, out);
}